// Round 4
// baseline (63.349 us; speedup 1.0000x reference)
//
#include <hip/hip_runtime.h>

#define B_ 8
#define T_ 2048
#define D_ 512
#define BT 128
#define BK 64
#define NT (T_/BT)              /* 16  */
#define NTILES (NT*(NT+1)/2)    /* 136 */
#define KTILES (D_/BK)          /* 8   */

typedef float f32x4 __attribute__((ext_vector_type(4)));
typedef __bf16 bf16x8 __attribute__((ext_vector_type(8)));

// order-preserving float<->uint encoding for atomicMax on possibly-negative floats
__device__ __forceinline__ unsigned encf(float f) {
    int i = __float_as_int(f);
    return (i < 0) ? ~((unsigned)i) : (((unsigned)i) | 0x80000000u);
}
__device__ __forceinline__ float decf(unsigned u) {
    unsigned b = (u & 0x80000000u) ? (u ^ 0x80000000u) : ~u;
    return __int_as_float((int)b);
}

__device__ __forceinline__ void gload_lds16(const __bf16* g, __bf16* l) {
    __builtin_amdgcn_global_load_lds(
        (const __attribute__((address_space(1))) unsigned int*)g,
        (__attribute__((address_space(3))) unsigned int*)l, 16, 0, 0);
}

// Kernel 1: xn[row] = bf16(x[row] / max(||x[row]||, 1e-12)); init msim to enc(-1)
__global__ __launch_bounds__(256) void rownorm_kernel(
        const float* __restrict__ x, __bf16* __restrict__ xn,
        unsigned* __restrict__ msim) {
    int row  = blockIdx.x * 4 + (threadIdx.x >> 6);
    int lane = threadIdx.x & 63;
    const float* p = x + (size_t)row * D_ + lane * 8;
    float4 a = *(const float4*)p;
    float4 b = *(const float4*)(p + 4);
    float ss = a.x*a.x + a.y*a.y + a.z*a.z + a.w*a.w
             + b.x*b.x + b.y*b.y + b.z*b.z + b.w*b.w;
#pragma unroll
    for (int m = 32; m; m >>= 1) ss += __shfl_xor(ss, m);
    float r = 1.0f / fmaxf(sqrtf(ss), 1e-12f);
    bf16x8 h;
    h[0] = (__bf16)(a.x * r); h[1] = (__bf16)(a.y * r);
    h[2] = (__bf16)(a.z * r); h[3] = (__bf16)(a.w * r);
    h[4] = (__bf16)(b.x * r); h[5] = (__bf16)(b.y * r);
    h[6] = (__bf16)(b.z * r); h[7] = (__bf16)(b.w * r);
    *(bf16x8*)(xn + (size_t)row * D_ + lane * 8) = h;
    if (lane == 0) msim[row] = 0x407FFFFFu;   // encf(-1.0f)
}

// Kernel 2: one block per (batch, lower-tri 128x128 tile). 4 waves (2x2).
// Double-buffered LDS with COUNTED vmcnt: next-tile A staged at the tile
// boundary before vmcnt(4) (stays in flight), B staged between the two
// 16-MFMA phases. One s_barrier per K-tile; lgkmcnt(0)+sched_barrier per
// phase; setprio(1) around MFMA clusters.
__global__ __launch_bounds__(256, 2) void simmax_kernel(
        const __bf16* __restrict__ xn, unsigned* __restrict__ msim) {
    __shared__ __attribute__((aligned(16))) __bf16 sA[2][BT * BK];
    __shared__ __attribute__((aligned(16))) __bf16 sB[2][BT * BK];

    int bid = blockIdx.x;
    int b   = bid & 7;        // batch -> XCD (round-robin dispatch)
    int s   = bid >> 3;       // 0..135 linear lower-tri tile id
    int it  = 0;
    while ((it + 1) * (it + 2) / 2 <= s) it++;
    int jt  = s - it * (it + 1) / 2;
    const bool diag = (it == jt);

    int tid  = threadIdx.x;
    int lane = tid & 63;
    int w    = tid >> 6;      // 0..3
    int wr   = w >> 1;        // wave row (64 rows)
    int wc   = w & 1;         // wave col (64 cols)
    int fr   = lane & 15;
    int kg   = lane >> 4;

    const size_t rowA0 = (size_t)b * T_ + (size_t)it * BT;
    const size_t rowB0 = (size_t)b * T_ + (size_t)jt * BT;

    // staging: per gload round p (0..3): rows p*32 + w*8 + (lane>>3).
    // HW writes wave-linearly (base + lane*16); source chunk pre-swizzled
    // so swizzled ds_reads see conflict-free layout (rule #21).
    int rb   = lane >> 3;              // 0..7
    int csrc = (lane & 7) ^ rb;        // pre-swizzled source chunk
    const __bf16* gA = xn + (rowA0 + w * 8 + rb) * D_ + csrc * 8;
    const __bf16* gB = xn + (rowB0 + w * 8 + rb) * D_ + csrc * 8;

    f32x4 acc[4][4];
#pragma unroll
    for (int m = 0; m < 4; m++)
#pragma unroll
        for (int n = 0; n < 4; n++)
            acc[m][n] = (f32x4){0.f, 0.f, 0.f, 0.f};

    int swz = (fr & 7) << 4;
    int laA = (wr * 64 + fr) * 128 + kg * 16;   // byte offsets, row stride 128B
    int laB = (wc * 64 + fr) * 128 + kg * 16;

#define STAGE_A(buf, kc) do {                                              \
    _Pragma("unroll")                                                      \
    for (int p = 0; p < 4; p++)                                            \
        gload_lds16(gA + (size_t)p * 32 * D_ + (kc) * BK,                  \
                    &sA[buf][(p * 32 + w * 8) * BK]);                      \
} while (0)
#define STAGE_B(buf, kc) do {                                              \
    _Pragma("unroll")                                                      \
    for (int p = 0; p < 4; p++)                                            \
        gload_lds16(gB + (size_t)p * 32 * D_ + (kc) * BK,                  \
                    &sB[buf][(p * 32 + w * 8) * BK]);                      \
} while (0)

    // prologue: stage tile 0
    STAGE_A(0, 0);
    if (!diag) STAGE_B(0, 0);

    for (int kc = 0; kc < KTILES; kc++) {
        int cur = kc & 1, nxt = cur ^ 1;
        // tile boundary: issue next A (stays in flight), drain current tile
        if (kc < KTILES - 1) {
            STAGE_A(nxt, kc + 1);
            asm volatile("s_waitcnt vmcnt(4)" ::: "memory");
        } else {
            asm volatile("s_waitcnt vmcnt(0)" ::: "memory");
        }
        __builtin_amdgcn_sched_barrier(0);
        asm volatile("s_barrier" ::: "memory");
        __builtin_amdgcn_sched_barrier(0);

        const char* bA = (const char*)&sA[cur][0];
        const char* bB = diag ? (const char*)&sA[cur][0]
                              : (const char*)&sB[cur][0];

        // ---- phase 0: all A frags + B n=0,1; 16 MFMA ----
        bf16x8 af[4][2], b0[2][2];
#pragma unroll
        for (int m = 0; m < 4; m++)
#pragma unroll
            for (int ks = 0; ks < 2; ks++)
                af[m][ks] = *(const bf16x8*)(bA +
                              ((laA + m * 2048 + ks * 64) ^ swz));
#pragma unroll
        for (int n = 0; n < 2; n++)
#pragma unroll
            for (int ks = 0; ks < 2; ks++)
                b0[n][ks] = *(const bf16x8*)(bB +
                              ((laB + n * 2048 + ks * 64) ^ swz));
        asm volatile("s_waitcnt lgkmcnt(0)" ::: "memory");
        __builtin_amdgcn_sched_barrier(0);
        __builtin_amdgcn_s_setprio(1);
#pragma unroll
        for (int m = 0; m < 4; m++)
#pragma unroll
            for (int n = 0; n < 2; n++)
#pragma unroll
                for (int ks = 0; ks < 2; ks++)
                    acc[m][n] = __builtin_amdgcn_mfma_f32_16x16x32_bf16(
                        af[m][ks], b0[n][ks], acc[m][n], 0, 0, 0);
        __builtin_amdgcn_s_setprio(0);
        __builtin_amdgcn_sched_barrier(0);

        // stage next B between phases (hides under phase-1 reads + MFMA)
        if (kc < KTILES - 1 && !diag) STAGE_B(nxt, kc + 1);

        // ---- phase 1: B n=2,3; 16 MFMA ----
        bf16x8 b1[2][2];
#pragma unroll
        for (int n = 0; n < 2; n++)
#pragma unroll
            for (int ks = 0; ks < 2; ks++)
                b1[n][ks] = *(const bf16x8*)(bB +
                              ((laB + (n + 2) * 2048 + ks * 64) ^ swz));
        asm volatile("s_waitcnt lgkmcnt(0)" ::: "memory");
        __builtin_amdgcn_sched_barrier(0);
        __builtin_amdgcn_s_setprio(1);
#pragma unroll
        for (int m = 0; m < 4; m++)
#pragma unroll
            for (int n = 0; n < 2; n++)
#pragma unroll
                for (int ks = 0; ks < 2; ks++)
                    acc[m][n + 2] = __builtin_amdgcn_mfma_f32_16x16x32_bf16(
                        af[m][ks], b1[n][ks], acc[m][n + 2], 0, 0, 0);
        __builtin_amdgcn_s_setprio(0);
        __builtin_amdgcn_sched_barrier(0);
    }
#undef STAGE_A
#undef STAGE_B

    // epilogue: causal mask (diag tiles only) + per-row max + atomicMax
    unsigned* mrow = msim + (size_t)b * T_ + (size_t)it * BT;
    const float NINF = -__builtin_inff();
#pragma unroll
    for (int m = 0; m < 4; m++) {
#pragma unroll
        for (int e = 0; e < 4; e++) {
            int rloc = wr * 64 + m * 16 + kg * 4 + e;
            float v = NINF;
#pragma unroll
            for (int n = 0; n < 4; n++) {
                int cloc = wc * 64 + n * 16 + fr;
                float t = acc[m][n][e];
                if (diag && cloc >= rloc) t = NINF;
                v = fmaxf(v, t);
            }
            v = fmaxf(v, __shfl_xor(v, 1));
            v = fmaxf(v, __shfl_xor(v, 2));
            v = fmaxf(v, __shfl_xor(v, 4));
            v = fmaxf(v, __shfl_xor(v, 8));
            if (fr == 0) atomicMax(&mrow[rloc], encf(v));
        }
    }
}

// Kernel 3: out = gelu_tanh(x * (1-alpha + alpha*exp(-tau*max_sim)))
__global__ __launch_bounds__(256) void gelu_kernel(
        const float* __restrict__ x, const unsigned* __restrict__ msim,
        const float* __restrict__ ltau, const float* __restrict__ lblend,
        float* __restrict__ out) {
    int i = blockIdx.x * 256 + threadIdx.x;   // float4 index
    float tau   = __expf(ltau[0]);
    float alpha = 1.f / (1.f + __expf(-lblend[0]));
    int row = i >> 7;                          // D_/4 = 128 float4 per row
    float ms = decf(msim[row]);
    float sc = (1.f - alpha) + alpha * __expf(-tau * ms);
    float4 v = ((const float4*)x)[i];
    const float c0 = 0.7978845608028654f;
    const float c1 = 0.044715f;
    float4 o;
#pragma unroll
    for (int j = 0; j < 4; j++) {
        float z = ((const float*)&v)[j] * sc;
        float u = c0 * (z + c1 * z * z * z);
        float t = __expf(2.f * u);
        float th = 1.f - 2.f / (t + 1.f);      // tanh(u), inf-safe
        ((float*)&o)[j] = 0.5f * z * (1.f + th);
    }
    ((float4*)out)[i] = o;
}

extern "C" void kernel_launch(void* const* d_in, const int* in_sizes, int n_in,
                              void* d_out, int out_size, void* d_ws, size_t ws_size,
                              hipStream_t stream) {
    (void)in_sizes; (void)n_in; (void)out_size; (void)ws_size;
    const float* x      = (const float*)d_in[0];
    const float* ltau   = (const float*)d_in[1];
    const float* lblend = (const float*)d_in[2];
    float*    out   = (float*)d_out;
    // xn (16.8 MB) lives in d_out until kernel3 overwrites it; msim in ws.
    __bf16*   xn    = (__bf16*)d_out;
    unsigned* msim  = (unsigned*)d_ws;

    rownorm_kernel<<<B_ * T_ / 4, 256, 0, stream>>>(x, xn, msim);
    simmax_kernel<<<B_ * NTILES, 256, 0, stream>>>(xn, msim);
    gelu_kernel<<<(B_ * T_ * D_ / 4) / 256, 256, 0, stream>>>(x, msim, ltau, lblend, out);
}

// Round 5
// 57.315 us; speedup vs baseline: 1.1053x; 1.1053x over previous
//
#include <hip/hip_runtime.h>

#define B_ 8
#define T_ 2048
#define D_ 512
#define BK 64
#define KT 8            /* K-tiles of 64 */
#define NBIG 28         /* strict lower-tri 256x256 tiles per batch */
#define NSMALL 24       /* 128x128 subtiles covering diag 256-blocks per batch */

typedef float f32x4 __attribute__((ext_vector_type(4)));
typedef __bf16 bf16x8 __attribute__((ext_vector_type(8)));

__device__ __forceinline__ unsigned encf(float f) {
    int i = __float_as_int(f);
    return (i < 0) ? ~((unsigned)i) : (((unsigned)i) | 0x80000000u);
}
__device__ __forceinline__ float decf(unsigned u) {
    unsigned b = (u & 0x80000000u) ? (u ^ 0x80000000u) : ~u;
    return __int_as_float((int)b);
}

__device__ __forceinline__ void gload_lds16(const __bf16* g, __bf16* l) {
    __builtin_amdgcn_global_load_lds(
        (const __attribute__((address_space(1))) unsigned int*)g,
        (__attribute__((address_space(3))) unsigned int*)l, 16, 0, 0);
}

// Kernel 1: xn[row] = bf16(x[row] / max(||x[row]||,1e-12)); init msim to enc(-1)
__global__ __launch_bounds__(256) void rownorm_kernel(
        const float* __restrict__ x, __bf16* __restrict__ xn,
        unsigned* __restrict__ msim) {
    int row  = blockIdx.x * 4 + (threadIdx.x >> 6);
    int lane = threadIdx.x & 63;
    const float* p = x + (size_t)row * D_ + lane * 8;
    float4 a = *(const float4*)p;
    float4 b = *(const float4*)(p + 4);
    float ss = a.x*a.x + a.y*a.y + a.z*a.z + a.w*a.w
             + b.x*b.x + b.y*b.y + b.z*b.z + b.w*b.w;
#pragma unroll
    for (int m = 32; m; m >>= 1) ss += __shfl_xor(ss, m);
    float r = 1.0f / fmaxf(sqrtf(ss), 1e-12f);
    bf16x8 h;
    h[0] = (__bf16)(a.x * r); h[1] = (__bf16)(a.y * r);
    h[2] = (__bf16)(a.z * r); h[3] = (__bf16)(a.w * r);
    h[4] = (__bf16)(b.x * r); h[5] = (__bf16)(b.y * r);
    h[6] = (__bf16)(b.z * r); h[7] = (__bf16)(b.w * r);
    *(bf16x8*)(xn + (size_t)row * D_ + lane * 8) = h;
    if (lane == 0) msim[row] = 0x407FFFFFu;   // encf(-1.0f)
}

// Kernel 2 (mixed grid): u<NBIG -> 256x256 off-diag tile (8 waves, deep
// pipeline, counted vmcnt(8), no mask). Else -> 128x128 subtile of a diag
// 256-block (quarter work, same skeleton, vmcnt(4), mask on diag subtiles).
__global__ __launch_bounds__(512, 2) void simmax_kernel(
        const __bf16* __restrict__ xn, unsigned* __restrict__ msim) {
    __shared__ __attribute__((aligned(16))) __bf16 sA[2][2][128 * BK];
    __shared__ __attribute__((aligned(16))) __bf16 sB[2][2][128 * BK];

    int bid  = blockIdx.x;
    int b    = bid & 7;          // batch -> XCD
    int u    = bid >> 3;         // 0..51 (bigs first: better back-fill)

    int tid  = threadIdx.x;
    int lane = tid & 63;
    int w    = tid >> 6;         // 0..7
    int wr   = w >> 2;           // 0..1
    int wc   = w & 3;            // 0..3
    int fr   = lane & 15;
    int kg   = lane >> 4;
    int rb   = lane >> 3;        // staging row-in-8
    int csrc = (lane & 7) ^ rb;  // pre-swizzled source chunk (rule #21)
    int swz  = (fr & 7) << 4;
    const float NINF = -__builtin_inff();

    if (u < NBIG) {
        // ---------------- BIG: 256x256, strict lower -> no mask ----------
        int it = 1; while (it * (it + 1) / 2 <= u) it++;
        int jt = u - it * (it - 1) / 2;
        const size_t rowA0 = (size_t)b * T_ + (size_t)it * 256;
        const size_t rowB0 = (size_t)b * T_ + (size_t)jt * 256;
        const __bf16* gA = xn + (rowA0 + w * 16 + rb) * D_ + csrc * 8;
        const __bf16* gB = xn + (rowB0 + w * 16 + rb) * D_ + csrc * 8;

#define STAGEB(s, kc) do {                                                  \
    _Pragma("unroll")                                                       \
    for (int h = 0; h < 2; h++)                                             \
    _Pragma("unroll")                                                       \
    for (int q = 0; q < 2; q++) {                                           \
        gload_lds16(gA + ((size_t)h * 128 + q * 8) * D_ + (kc) * BK,        \
                    &sA[s][h][(w * 16 + q * 8) * BK]);                      \
        gload_lds16(gB + ((size_t)h * 128 + q * 8) * D_ + (kc) * BK,        \
                    &sB[s][h][(w * 16 + q * 8) * BK]);                      \
    } } while (0)

        f32x4 acc[8][4];
#pragma unroll
        for (int m = 0; m < 8; m++)
#pragma unroll
            for (int n = 0; n < 4; n++)
                acc[m][n] = (f32x4){0.f, 0.f, 0.f, 0.f};

        // prologue: two K-tiles in flight
        STAGEB(0, 0);
        STAGEB(1, 1);
        asm volatile("s_waitcnt vmcnt(8)" ::: "memory");   // kt0 landed (own)
        __builtin_amdgcn_sched_barrier(0);
        asm volatile("s_barrier" ::: "memory");            // all waves' kt0

        int laA = fr * 128 + kg * 16;                  // A: within-half, +m*2048
        int laB = ((wc & 1) * 64 + fr) * 128 + kg * 16;

        for (int kt = 0; kt < KT; kt++) {
            int s = kt & 1;
            const char* bA = (const char*)&sA[s][wr][0];
            const char* bB = (const char*)&sB[s][wc >> 1][0];

            bf16x8 af[8][2], bf[2][2];
            // P1: A m0-3 + B n0-1 -> Q(0,0)
#pragma unroll
            for (int m = 0; m < 4; m++)
#pragma unroll
                for (int ks = 0; ks < 2; ks++)
                    af[m][ks] = *(const bf16x8*)(bA + ((laA + m * 2048 + ks * 64) ^ swz));
#pragma unroll
            for (int n = 0; n < 2; n++)
#pragma unroll
                for (int ks = 0; ks < 2; ks++)
                    bf[n][ks] = *(const bf16x8*)(bB + ((laB + n * 2048 + ks * 64) ^ swz));
            asm volatile("s_waitcnt lgkmcnt(0)" ::: "memory");
            __builtin_amdgcn_sched_barrier(0);
            __builtin_amdgcn_s_setprio(1);
#pragma unroll
            for (int m = 0; m < 4; m++)
#pragma unroll
                for (int n = 0; n < 2; n++)
#pragma unroll
                    for (int ks = 0; ks < 2; ks++)
                        acc[m][n] = __builtin_amdgcn_mfma_f32_16x16x32_bf16(
                            af[m][ks], bf[n][ks], acc[m][n], 0, 0, 0);
            __builtin_amdgcn_s_setprio(0);
            __builtin_amdgcn_sched_barrier(0);

            // P2: A m4-7 -> Q(1,0)
#pragma unroll
            for (int m = 4; m < 8; m++)
#pragma unroll
                for (int ks = 0; ks < 2; ks++)
                    af[m][ks] = *(const bf16x8*)(bA + ((laA + m * 2048 + ks * 64) ^ swz));
            asm volatile("s_waitcnt lgkmcnt(0)" ::: "memory");
            __builtin_amdgcn_sched_barrier(0);
            __builtin_amdgcn_s_setprio(1);
#pragma unroll
            for (int m = 4; m < 8; m++)
#pragma unroll
                for (int n = 0; n < 2; n++)
#pragma unroll
                    for (int ks = 0; ks < 2; ks++)
                        acc[m][n] = __builtin_amdgcn_mfma_f32_16x16x32_bf16(
                            af[m][ks], bf[n][ks], acc[m][n], 0, 0, 0);
            __builtin_amdgcn_s_setprio(0);
            __builtin_amdgcn_sched_barrier(0);

            // P3: B n2-3 -> Q(0,1)
#pragma unroll
            for (int n = 0; n < 2; n++)
#pragma unroll
                for (int ks = 0; ks < 2; ks++)
                    bf[n][ks] = *(const bf16x8*)(bB + ((laB + (n + 2) * 2048 + ks * 64) ^ swz));
            asm volatile("s_waitcnt lgkmcnt(0)" ::: "memory");
            __builtin_amdgcn_sched_barrier(0);
            __builtin_amdgcn_s_setprio(1);
#pragma unroll
            for (int m = 0; m < 4; m++)
#pragma unroll
                for (int n = 0; n < 2; n++)
#pragma unroll
                    for (int ks = 0; ks < 2; ks++)
                        acc[m][n + 2] = __builtin_amdgcn_mfma_f32_16x16x32_bf16(
                            af[m][ks], bf[n][ks], acc[m][n + 2], 0, 0, 0);
            __builtin_amdgcn_s_setprio(0);
            __builtin_amdgcn_sched_barrier(0);

            // P4: Q(1,1)
            __builtin_amdgcn_s_setprio(1);
#pragma unroll
            for (int m = 4; m < 8; m++)
#pragma unroll
                for (int n = 0; n < 2; n++)
#pragma unroll
                    for (int ks = 0; ks < 2; ks++)
                        acc[m][n + 2] = __builtin_amdgcn_mfma_f32_16x16x32_bf16(
                            af[m][ks], bf[n][ks], acc[m][n + 2], 0, 0, 0);
            __builtin_amdgcn_s_setprio(0);
            __builtin_amdgcn_sched_barrier(0);

            if (kt == KT - 1) break;
            // boundary: free slot s, refill it for kt+2, wait kt+1 landed
            asm volatile("s_barrier" ::: "memory");        // all done reading s
            if (kt + 2 < KT) {
                STAGEB(s, kt + 2);
                asm volatile("s_waitcnt vmcnt(8)" ::: "memory");
            } else {
                asm volatile("s_waitcnt vmcnt(0)" ::: "memory");
            }
            __builtin_amdgcn_sched_barrier(0);
            asm volatile("s_barrier" ::: "memory");        // kt+1 visible to all
        }
#undef STAGEB

        unsigned* mrow = msim + rowA0;
#pragma unroll
        for (int m = 0; m < 8; m++) {
#pragma unroll
            for (int e = 0; e < 4; e++) {
                int rloc = wr * 128 + m * 16 + kg * 4 + e;
                float v = NINF;
#pragma unroll
                for (int n = 0; n < 4; n++) v = fmaxf(v, acc[m][n][e]);
                v = fmaxf(v, __shfl_xor(v, 1));
                v = fmaxf(v, __shfl_xor(v, 2));
                v = fmaxf(v, __shfl_xor(v, 4));
                v = fmaxf(v, __shfl_xor(v, 8));
                if (fr == 0) atomicMax(&mrow[rloc], encf(v));
            }
        }
    } else {
        // ------------- SMALL: 128x128 subtile of a diag 256-block --------
        int u2 = u - NBIG;               // 0..23
        int d  = u2 / 3, r = u2 - 3 * d;
        int it = 2 * d + (r >= 1 ? 1 : 0);
        int jt = 2 * d + (r == 2 ? 1 : 0);
        const bool diag = (r != 1);
        const size_t rowA0 = (size_t)b * T_ + (size_t)it * 128;
        const size_t rowB0 = (size_t)b * T_ + (size_t)jt * 128;
        const __bf16* gA = xn + (rowA0 + w * 16 + rb) * D_ + csrc * 8;
        const __bf16* gB = xn + (rowB0 + w * 16 + rb) * D_ + csrc * 8;

#define STAGES(s, kc) do {                                                  \
    _Pragma("unroll")                                                       \
    for (int q = 0; q < 2; q++) {                                           \
        gload_lds16(gA + (size_t)q * 8 * D_ + (kc) * BK,                    \
                    &sA[s][0][(w * 16 + q * 8) * BK]);                      \
        gload_lds16(gB + (size_t)q * 8 * D_ + (kc) * BK,                    \
                    &sB[s][0][(w * 16 + q * 8) * BK]);                      \
    } } while (0)

        f32x4 acc[4][2];
#pragma unroll
        for (int m = 0; m < 4; m++)
#pragma unroll
            for (int n = 0; n < 2; n++)
                acc[m][n] = (f32x4){0.f, 0.f, 0.f, 0.f};

        STAGES(0, 0);
        STAGES(1, 1);
        asm volatile("s_waitcnt vmcnt(4)" ::: "memory");
        __builtin_amdgcn_sched_barrier(0);
        asm volatile("s_barrier" ::: "memory");

        int laA = (wr * 64 + fr) * 128 + kg * 16;   // rows wr*64+m*16+fr
        int laB = (wc * 32 + fr) * 128 + kg * 16;   // rows wc*32+n*16+fr

        for (int kt = 0; kt < KT; kt++) {
            int s = kt & 1;
            const char* bA = (const char*)&sA[s][0][0];
            const char* bB = (const char*)&sB[s][0][0];
            bf16x8 af[4][2], bf[2][2];
#pragma unroll
            for (int m = 0; m < 4; m++)
#pragma unroll
                for (int ks = 0; ks < 2; ks++)
                    af[m][ks] = *(const bf16x8*)(bA + ((laA + m * 2048 + ks * 64) ^ swz));
#pragma unroll
            for (int n = 0; n < 2; n++)
#pragma unroll
                for (int ks = 0; ks < 2; ks++)
                    bf[n][ks] = *(const bf16x8*)(bB + ((laB + n * 2048 + ks * 64) ^ swz));
            asm volatile("s_waitcnt lgkmcnt(0)" ::: "memory");
            __builtin_amdgcn_sched_barrier(0);
            __builtin_amdgcn_s_setprio(1);
#pragma unroll
            for (int m = 0; m < 4; m++)
#pragma unroll
                for (int n = 0; n < 2; n++)
#pragma unroll
                    for (int ks = 0; ks < 2; ks++)
                        acc[m][n] = __builtin_amdgcn_mfma_f32_16x16x32_bf16(
                            af[m][ks], bf[n][ks], acc[m][n], 0, 0, 0);
            __builtin_amdgcn_s_setprio(0);
            __builtin_amdgcn_sched_barrier(0);

            if (kt == KT - 1) break;
            asm volatile("s_barrier" ::: "memory");
            if (kt + 2 < KT) {
                STAGES(s, kt + 2);
                asm volatile("s_waitcnt vmcnt(4)" ::: "memory");
            } else {
                asm volatile("s_waitcnt vmcnt(0)" ::: "memory");
            }
            __builtin_amdgcn_sched_barrier(0);
            asm volatile("s_barrier" ::: "memory");
        }
#undef STAGES

        unsigned* mrow = msim + rowA0;
#pragma unroll
        for (int m = 0; m < 4; m++) {
#pragma unroll
            for (int e = 0; e < 4; e++) {
                int rloc = wr * 64 + m * 16 + kg * 4 + e;
                float v = NINF;
#pragma unroll
                for (int n = 0; n < 2; n++) {
                    int cloc = wc * 32 + n * 16 + fr;
                    float t = acc[m][n][e];
                    if (diag && cloc >= rloc) t = NINF;
                    v = fmaxf(v, t);
                }
                v = fmaxf(v, __shfl_xor(v, 1));
                v = fmaxf(v, __shfl_xor(v, 2));
                v = fmaxf(v, __shfl_xor(v, 4));
                v = fmaxf(v, __shfl_xor(v, 8));
                if (fr == 0) atomicMax(&mrow[rloc], encf(v));
            }
        }
    }
}

// Kernel 3: out = gelu_tanh(x * (1-alpha + alpha*exp(-tau*max_sim)))
__global__ __launch_bounds__(256) void gelu_kernel(
        const float* __restrict__ x, const unsigned* __restrict__ msim,
        const float* __restrict__ ltau, const float* __restrict__ lblend,
        float* __restrict__ out) {
    int i = blockIdx.x * 256 + threadIdx.x;   // float4 index
    float tau   = __expf(ltau[0]);
    float alpha = 1.f / (1.f + __expf(-lblend[0]));
    int row = i >> 7;                          // D_/4 = 128 float4 per row
    float ms = decf(msim[row]);
    float sc = (1.f - alpha) + alpha * __expf(-tau * ms);
    float4 v = ((const float4*)x)[i];
    const float c0 = 0.7978845608028654f;
    const float c1 = 0.044715f;
    float4 o;
#pragma unroll
    for (int j = 0; j < 4; j++) {
        float z = ((const float*)&v)[j] * sc;
        float uu = c0 * (z + c1 * z * z * z);
        float t = __expf(2.f * uu);
        float th = 1.f - 2.f / (t + 1.f);      // tanh, inf-safe
        ((float*)&o)[j] = 0.5f * z * (1.f + th);
    }
    ((float4*)out)[i] = o;
}

extern "C" void kernel_launch(void* const* d_in, const int* in_sizes, int n_in,
                              void* d_out, int out_size, void* d_ws, size_t ws_size,
                              hipStream_t stream) {
    (void)in_sizes; (void)n_in; (void)out_size; (void)ws_size;
    const float* x      = (const float*)d_in[0];
    const float* ltau   = (const float*)d_in[1];
    const float* lblend = (const float*)d_in[2];
    float*    out   = (float*)d_out;
    // xn (16.8 MB) lives in d_out until gelu overwrites it; msim in ws.
    __bf16*   xn    = (__bf16*)d_out;
    unsigned* msim  = (unsigned*)d_ws;

    rownorm_kernel<<<B_ * T_ / 4, 256, 0, stream>>>(x, xn, msim);
    simmax_kernel<<<B_ * (NBIG + NSMALL), 512, 0, stream>>>(xn, msim);
    gelu_kernel<<<(B_ * T_ * D_ / 4) / 256, 256, 0, stream>>>(x, msim, ltau, lblend, out);
}